// Round 1
// baseline (182.421 us; speedup 1.0000x reference)
//
#include <hip/hip_runtime.h>

typedef float f32x4 __attribute__((ext_vector_type(4)));
typedef __bf16 bf16x8 __attribute__((ext_vector_type(8)));
typedef unsigned short us8 __attribute__((ext_vector_type(8)));
typedef unsigned short us4 __attribute__((ext_vector_type(4)));

#define QSCALE 11.541560327111707f   // 8 * log2(e) -> softmax in exp2 domain
#define NEG_INF (-__builtin_inff())

__device__ __forceinline__ float fexp2(float x) {
    return __builtin_amdgcn_exp2f(x);
}
__device__ __forceinline__ unsigned short f2bf(float x) {   // round-nearest
    unsigned u = __builtin_bit_cast(unsigned, x);
    u += 0x7fffu + ((u >> 16) & 1u);
    return (unsigned short)(u >> 16);
}
__device__ __forceinline__ float bf2f(unsigned short h) {
    unsigned u = ((unsigned)h) << 16;
    return __builtin_bit_cast(float, u);
}
__device__ __forceinline__ unsigned short bftrunc(float x) { // truncate
    return (unsigned short)(__builtin_bit_cast(unsigned, x) >> 16);
}
__device__ __forceinline__ f32x4 mfma16(us8 a, us8 b, f32x4 c) {
    return __builtin_amdgcn_mfma_f32_16x16x32_bf16(
        __builtin_bit_cast(bf16x8, a), __builtin_bit_cast(bf16x8, b), c, 0, 0, 0);
}
__device__ __forceinline__ void glds16(const unsigned short* g, unsigned short* l) {
    __builtin_amdgcn_global_load_lds(
        (const __attribute__((address_space(1))) unsigned int*)g,
        (__attribute__((address_space(3))) unsigned int*)l, 16, 0, 0);
}
__device__ __forceinline__ void splitx(float4 a, float4 b, us8& h, us8& lo) {
    float xf[8] = {a.x, a.y, a.z, a.w, b.x, b.y, b.z, b.w};
#pragma unroll
    for (int e = 0; e < 8; ++e) {
        unsigned u = __builtin_bit_cast(unsigned, xf[e]);
        h[e] = (unsigned short)(u >> 16);
        lo[e] = bftrunc(xf[e] - __builtin_bit_cast(float, u & 0xffff0000u));
    }
}

// ---------------- Kernel 0: W transpose + split (RN split) ----------------
__global__ __launch_bounds__(256) void wprep_kernel(
    const float* __restrict__ Wq, const float* __restrict__ Wk,
    const float* __restrict__ Wv,
    unsigned short* __restrict__ Wthi, unsigned short* __restrict__ Wtlo)
{
    __shared__ __align__(16) float Ls[64][68];
    const int g = blockIdx.x >> 4;
    const int k0 = (blockIdx.x & 15) << 6;
    const float* W = (g == 0) ? Wq : (g == 1) ? Wk : Wv;
    const int t = threadIdx.x;
#pragma unroll
    for (int u = 0; u < 4; ++u) {
        int idx = t + (u << 8);
        int row = idx >> 4, c4 = (idx & 15) << 2;
        *(float4*)&Ls[row][c4] = *(const float4*)&W[(size_t)(k0 + row) * 64 + c4];
    }
    __syncthreads();
    const int h = t >> 2, kk0 = (t & 3) << 4;
    size_t base = (size_t)((g << 6) + h) * 1024 + k0 + kk0;
#pragma unroll
    for (int c = 0; c < 4; ++c) {
        us4 hv, lv;
#pragma unroll
        for (int i = 0; i < 4; ++i) {
            float x = Ls[kk0 + (c << 2) + i][h];
            unsigned short hh = f2bf(x);
            hv[i] = hh;
            lv[i] = f2bf(x - bf2f(hh));
        }
        *(us4*)&Wthi[base + (c << 2)] = hv;
        *(us4*)&Wtlo[base + (c << 2)] = lv;
    }
}

// ---------------- Kernel 1: fused QKV projection ----------------
// v2: 32x96 tile, grid (512,2) = 4 blocks/CU (was 2). K-step 64.
// X: fp32 global -> regs -> trunc-split IN REGISTERS during MFMA phase of the
// previous iter (off the inter-barrier critical path) -> swizzled LDS store.
// W-hi: double-buffered glds16.  W-lo: direct per-lane global frags (L1/L2).
// Q written pre-scaled by 8*log2(e).
__global__ __launch_bounds__(256, 4) void qkv_kernel(
    const float* __restrict__ X,
    const unsigned short* __restrict__ Wthi,
    const unsigned short* __restrict__ Wtlo,
    unsigned short* __restrict__ Qhi, unsigned short* __restrict__ Qlo,
    unsigned short* __restrict__ Khi, unsigned short* __restrict__ Klo,
    unsigned short* __restrict__ Vthi)
{
    __shared__ __align__(16) unsigned short sm[17664];  // 34.5 KB
    unsigned short* Xh = sm;                 // 32x64, swizzled (2048)
    unsigned short* Xl = sm + 2048;          // 2048
    unsigned short* Wh = sm + 4096;          // 2 buf x 6144 (96x64 swizzled)
    unsigned short* Vx = sm + 16384;         // 4x16x20 transpose scratch

    const int t = threadIdx.x;
    const int w = t >> 6, l = t & 63, lm = l & 15, lg = (l >> 4) & 3;
    const int wq = w >> 1, wc = w & 1;
    const int m0 = blockIdx.x << 5;
    const int y  = blockIdx.y;

    // --- W-hi glds staging: 3 x 1KB per wave per iter (8 rows each) ---
    const unsigned short* gsrc[3];
    int gdst[3];
#pragma unroll
    for (int i = 0; i < 3; ++i) {
        int g = w * 3 + i;                      // 0..11
        int n = (g << 3) + (l >> 3);            // W row 0..95
        int cg = (l & 7) ^ ((l >> 3) & 7);      // swizzled source chunk
        gsrc[i] = Wthi + (size_t)(y * 96 + n) * 1024 + (cg << 3);
        gdst[i] = g << 9;                       // g*512 us
    }
    // --- X staging: thread -> 8 floats (row t>>3, chunk t&7) ---
    const int xrow = t >> 3;
    const int xch  = t & 7;
    const float* xptr = X + (size_t)(m0 + xrow) * 1024 + (xch << 3);
    unsigned short* xwh = Xh + (xrow << 6) + ((xch ^ (xrow & 7)) << 3);
    unsigned short* xwl = Xl + (xrow << 6) + ((xch ^ (xrow & 7)) << 3);

    // --- fragment LDS offsets (swizzle: slot = (kc*4+lg) ^ (lm&7)) ---
    int aoff[2], boff[3][2];
#pragma unroll
    for (int kc = 0; kc < 2; ++kc) {
        int m = (wq << 4) + lm;
        aoff[kc] = (m << 6) + ((((kc << 2) + lg) ^ (lm & 7)) << 3);
    }
#pragma unroll
    for (int ct = 0; ct < 3; ++ct)
#pragma unroll
        for (int kc = 0; kc < 2; ++kc) {
            int n = wc * 48 + (ct << 4) + lm;
            boff[ct][kc] = (n << 6) + ((((kc << 2) + lg) ^ (lm & 7)) << 3);
        }
    // --- W-lo direct global fragment pointers ---
    const unsigned short* wlp[3][2];
#pragma unroll
    for (int ct = 0; ct < 3; ++ct)
#pragma unroll
        for (int kc = 0; kc < 2; ++kc)
            wlp[ct][kc] = Wtlo + (size_t)(y * 96 + wc * 48 + (ct << 4) + lm) * 1024
                               + (kc << 5) + (lg << 3);

    f32x4 acc[3];
#pragma unroll
    for (int j = 0; j < 3; ++j) acc[j] = (f32x4){0.f, 0.f, 0.f, 0.f};

    // prologue: W(0) -> buf0; X(0) -> regs -> split; X(1) -> regs
#pragma unroll
    for (int i = 0; i < 3; ++i) glds16(gsrc[i], Wh + gdst[i]);
    float4 xv0 = *(const float4*)(xptr);
    float4 xv1 = *(const float4*)(xptr + 4);
    us8 ch, cl;
    splitx(xv0, xv1, ch, cl);
    xv0 = *(const float4*)(xptr + 64);
    xv1 = *(const float4*)(xptr + 68);

    for (int k = 0; k < 16; ++k) {
        const int wb = (k & 1) * 6144;
        __syncthreads();                                   // A: prev readers done
        *(us8*)xwh = ch;                                   // store X(k) (2 ds_writes)
        *(us8*)xwl = cl;
        if (k < 15) {
            const int ko = (k + 1) << 6;
            const int nb = 6144 - wb;
#pragma unroll
            for (int i = 0; i < 3; ++i) glds16(gsrc[i] + ko, Wh + nb + gdst[i]);
        }
        __syncthreads();                                   // B: stage visible
        if (k < 15) {
            splitx(xv0, xv1, ch, cl);                      // convert X(k+1) in regs
            if (k < 14) {
                const int ko2 = (k + 2) << 6;
                xv0 = *(const float4*)(xptr + ko2);
                xv1 = *(const float4*)(xptr + ko2 + 4);
            }
        }
        us8 bl[3][2];
#pragma unroll
        for (int ct = 0; ct < 3; ++ct)
#pragma unroll
            for (int kc = 0; kc < 2; ++kc)
                bl[ct][kc] = *(const us8*)(wlp[ct][kc] + (k << 6));
        us8 ah[2], al[2], bh[3][2];
#pragma unroll
        for (int kc = 0; kc < 2; ++kc) {
            ah[kc] = *(const us8*)&Xh[aoff[kc]];
            al[kc] = *(const us8*)&Xl[aoff[kc]];
        }
#pragma unroll
        for (int ct = 0; ct < 3; ++ct)
#pragma unroll
            for (int kc = 0; kc < 2; ++kc)
                bh[ct][kc] = *(const us8*)&Wh[wb + boff[ct][kc]];
        // LDS-only terms first (hi*hi, lo*hi), then terms needing W-lo globals
#pragma unroll
        for (int kc = 0; kc < 2; ++kc)
#pragma unroll
            for (int ct = 0; ct < 3; ++ct) {
                acc[ct] = mfma16(ah[kc], bh[ct][kc], acc[ct]);
                acc[ct] = mfma16(al[kc], bh[ct][kc], acc[ct]);
            }
#pragma unroll
        for (int kc = 0; kc < 2; ++kc)
#pragma unroll
            for (int ct = 0; ct < 3; ++ct)
                acc[ct] = mfma16(ah[kc], bl[ct][kc], acc[ct]);
    }

    // epilogue: trunc-split stores; Q pre-scaled; V transposed via Vx
    const int tbr = m0 + (wq << 4);
#pragma unroll
    for (int ct = 0; ct < 3; ++ct) {
        const int gc = y * 96 + wc * 48 + (ct << 4);
        if (gc < 128) {
            unsigned short* Dh = (gc < 64) ? Qhi : Khi;
            unsigned short* Dl = (gc < 64) ? Qlo : Klo;
            const float sc = (gc < 64) ? QSCALE : 1.0f;
            const int colb = (gc & 63) + lm;
#pragma unroll
            for (int r = 0; r < 4; ++r) {
                int row = tbr + (lg << 2) + r;
                float x = acc[ct][r] * sc;
                unsigned u = __builtin_bit_cast(unsigned, x);
                size_t o = (size_t)row * 64 + colb;
                Dh[o] = (unsigned short)(u >> 16);
                Dl[o] = bftrunc(x - __builtin_bit_cast(float, u & 0xffff0000u));
            }
        } else {
            // V: 16x16 transpose via wave-local LDS
#pragma unroll
            for (int r = 0; r < 4; ++r)
                Vx[w * 320 + lm * 20 + (lg << 2) + r] = bftrunc(acc[ct][r]);
            __asm__ volatile("" ::: "memory");
            const int h0 = gc - 128;
            const int tb = tbr;
            const int bb = tb >> 11;
            const int tl = (tb & 2047) + ((l & 3) << 2);
            const int hh2 = h0 + (l >> 2);
            us4 vv = *(const us4*)&Vx[w * 320 + (l >> 2) * 20 + ((l & 3) << 2)];
            *(us4*)&Vthi[(size_t)((bb << 6) + hh2) * 2048 + tl] = vv;
            __asm__ volatile("" ::: "memory");
        }
    }
}

// ---------------- Kernel 2: causal flash attention ----------------
// 512 blocks = (b, 32-row q-tile, heavy-first). 4 waves = 4 key-parities,
// ZERO barriers in the K-loop (K/V frags direct from global, L2-resident).
// S^T layout: lane = q-row -> softmax reduce = 15 local ops + 2 shuffles.
// exp2 domain (Q pre-scaled by 8*log2e). 4-way merge at end.
__global__ __launch_bounds__(256, 2) void attn_kernel(
    const unsigned short* __restrict__ Qhi, const unsigned short* __restrict__ Qlo,
    const unsigned short* __restrict__ Khi, const unsigned short* __restrict__ Klo,
    const unsigned short* __restrict__ Vthi,
    float* __restrict__ O)
{
    __shared__ __align__(16) unsigned char smem[33792];
    unsigned short* PS = (unsigned short*)smem;     // [4][32][72] us (loop phase)
    float* FO = (float*)smem;                       // [4][32][64] f32 (merge phase)
    float* FM = (float*)(smem + 32768);             // [4][32]
    float* FL = FM + 128;

    const int t = threadIdx.x;
    const int w = t >> 6, l = t & 63, lm = l & 15, lg = (l >> 4) & 3;
    const int b = blockIdx.x & 7;
    const int qp = 63 - (blockIdx.x >> 3);          // heavy tiles first
    const int nk = (qp >> 1) + 1;                   // 64-key tiles needed
    const int q0 = qp << 5;
    const size_t brow = (size_t)b << 11;

    // Q fragments pinned (B-operand: lane=qrow, k=lg*8+j)
    us8 qh[2][2], ql[2][2];
#pragma unroll
    for (int nt = 0; nt < 2; ++nt)
#pragma unroll
        for (int kc = 0; kc < 2; ++kc) {
            size_t off = (brow + q0 + (nt << 4) + lm) * 64 + (kc << 5) + (lg << 3);
            qh[nt][kc] = *(const us8*)&Qhi[off];
            ql[nt][kc] = *(const us8*)&Qlo[off];
        }

    f32x4 o_acc[2][4];
#pragma unroll
    for (int nt = 0; nt < 2; ++nt)
#pragma unroll
        for (int ct = 0; ct < 4; ++ct) o_acc[nt][ct] = (f32x4){0.f, 0.f, 0.f, 0.f};
    float m_r[2] = {NEG_INF, NEG_INF}, l_r[2] = {0.f, 0.f};
    unsigned short* ps = PS + w * 2304;             // wave-local 32x72

    for (int j = w; j < nk; j += 4) {
        const int kk0 = j << 6;
        us8 kh[4][2], klo[4][2], vh[4][2];
#pragma unroll
        for (int mt = 0; mt < 4; ++mt)
#pragma unroll
            for (int kc = 0; kc < 2; ++kc) {
                size_t off = (brow + kk0 + (mt << 4) + lm) * 64 + (kc << 5) + (lg << 3);
                kh[mt][kc] = *(const us8*)&Khi[off];
                klo[mt][kc] = *(const us8*)&Klo[off];
            }
#pragma unroll
        for (int ct = 0; ct < 4; ++ct)
#pragma unroll
            for (int kc = 0; kc < 2; ++kc) {
                size_t off = ((size_t)(b << 6) + (ct << 4) + lm) * 2048
                           + kk0 + (kc << 5) + (lg << 3);
                vh[ct][kc] = *(const us8*)&Vthi[off];
            }
        // S^T = K Q^T (split-bf16)
        f32x4 s[4][2];
#pragma unroll
        for (int mt = 0; mt < 4; ++mt)
#pragma unroll
            for (int nt = 0; nt < 2; ++nt) s[mt][nt] = (f32x4){0.f, 0.f, 0.f, 0.f};
#pragma unroll
        for (int kc = 0; kc < 2; ++kc)
#pragma unroll
            for (int mt = 0; mt < 4; ++mt)
#pragma unroll
                for (int nt = 0; nt < 2; ++nt) {
                    s[mt][nt] = mfma16(kh[mt][kc], qh[nt][kc], s[mt][nt]);
                    s[mt][nt] = mfma16(klo[mt][kc], qh[nt][kc], s[mt][nt]);
                    s[mt][nt] = mfma16(kh[mt][kc], ql[nt][kc], s[mt][nt]);
                }
        // online softmax (exp2 domain), lane owns row q0+nt*16+lm, 16 keys
        float alz[2];
#pragma unroll
        for (int nt = 0; nt < 2; ++nt) {
            const int qr = q0 + (nt << 4) + lm;
            float sv[16];
            if ((kk0 + 63) <= (q0 + (nt << 4))) {
#pragma unroll
                for (int mt = 0; mt < 4; ++mt)
#pragma unroll
                    for (int r = 0; r < 4; ++r) sv[(mt << 2) + r] = s[mt][nt][r];
            } else {
#pragma unroll
                for (int mt = 0; mt < 4; ++mt)
#pragma unroll
                    for (int r = 0; r < 4; ++r) {
                        const int key = kk0 + (mt << 4) + (lg << 2) + r;
                        sv[(mt << 2) + r] = (key <= qr) ? s[mt][nt][r] : NEG_INF;
                    }
            }
            float t8[8];
#pragma unroll
            for (int i = 0; i < 8; ++i) t8[i] = fmaxf(sv[i], sv[i + 8]);
#pragma unroll
            for (int i = 0; i < 4; ++i) t8[i] = fmaxf(t8[i], t8[i + 4]);
            float mx = fmaxf(fmaxf(t8[0], t8[1]), fmaxf(t8[2], t8[3]));
            mx = fmaxf(mx, __shfl_xor(mx, 16));
            mx = fmaxf(mx, __shfl_xor(mx, 32));
            const float mn = fmaxf(m_r[nt], mx);
            alz[nt] = fexp2(m_r[nt] - mn);
            m_r[nt] = mn;
            float p[16];
#pragma unroll
            for (int i = 0; i < 16; ++i) p[i] = fexp2(sv[i] - mn);
#pragma unroll
            for (int mt = 0; mt < 4; ++mt) {
                us4 pk;
#pragma unroll
                for (int r = 0; r < 4; ++r) pk[r] = bftrunc(p[(mt << 2) + r]);
                *(us4*)&ps[((nt << 4) + lm) * 72 + (mt << 4) + (lg << 2)] = pk;
            }
            float s8[8];
#pragma unroll
            for (int i = 0; i < 8; ++i) s8[i] = p[i] + p[i + 8];
#pragma unroll
            for (int i = 0; i < 4; ++i) s8[i] = s8[i] + s8[i + 4];
            float rs = (s8[0] + s8[1]) + (s8[2] + s8[3]);
            rs += __shfl_xor(rs, 16);
            rs += __shfl_xor(rs, 32);
            l_r[nt] = l_r[nt] * alz[nt] + rs;
        }
        __asm__ volatile("" ::: "memory");   // P write -> read, same wave
        // rescale O (alz lives at lane=row; fetch via shuffle)
#pragma unroll
        for (int nt = 0; nt < 2; ++nt)
#pragma unroll
            for (int r = 0; r < 4; ++r) {
                const float av = __shfl(alz[nt], (lg << 2) + r);
#pragma unroll
                for (int ct = 0; ct < 4; ++ct) o_acc[nt][ct][r] *= av;
            }
        // O += P V
#pragma unroll
        for (int nt = 0; nt < 2; ++nt)
#pragma unroll
            for (int kc = 0; kc < 2; ++kc) {
                us8 pa = *(const us8*)&ps[((nt << 4) + lm) * 72 + (kc << 5) + (lg << 3)];
#pragma unroll
                for (int ct = 0; ct < 4; ++ct)
                    o_acc[nt][ct] = mfma16(pa, vh[ct][kc], o_acc[nt][ct]);
            }
    }

    // ---- 4-way key-parity merge ----
    __syncthreads();                         // all PS use done before FO alias
#pragma unroll
    for (int nt = 0; nt < 2; ++nt)
#pragma unroll
        for (int ct = 0; ct < 4; ++ct)
#pragma unroll
            for (int r = 0; r < 4; ++r)
                FO[(w << 11) + (((nt << 4) + (lg << 2) + r) << 6) + (ct << 4) + lm]
                    = o_acc[nt][ct][r];
    if (l < 16) {
        FM[(w << 5) + lm] = m_r[0]; FM[(w << 5) + 16 + lm] = m_r[1];
        FL[(w << 5) + lm] = l_r[0]; FL[(w << 5) + 16 + lm] = l_r[1];
    }
    __syncthreads();
    const int jr = t >> 3;                   // row 0..31
    const int cg = (t & 7) << 3;             // col base
    float m0v = FM[jr], m1v = FM[32 + jr], m2v = FM[64 + jr], m3v = FM[96 + jr];
    float mm = fmaxf(fmaxf(m0v, m1v), fmaxf(m2v, m3v));
    float a0 = fexp2(m0v - mm), a1 = fexp2(m1v - mm);
    float a2 = fexp2(m2v - mm), a3 = fexp2(m3v - mm);
    float L = a0 * FL[jr] + a1 * FL[32 + jr] + a2 * FL[64 + jr] + a3 * FL[96 + jr];
    float inv = 1.0f / L;
    float ov[8];
#pragma unroll
    for (int c = 0; c < 8; ++c)
        ov[c] = a0 * FO[(jr << 6) + cg + c] + a1 * FO[2048 + (jr << 6) + cg + c]
              + a2 * FO[4096 + (jr << 6) + cg + c] + a3 * FO[6144 + (jr << 6) + cg + c];
    float4 o1 = {ov[0] * inv, ov[1] * inv, ov[2] * inv, ov[3] * inv};
    float4 o2 = {ov[4] * inv, ov[5] * inv, ov[6] * inv, ov[7] * inv};
    float* op = O + (brow + q0 + jr) * 64 + cg;
    *(float4*)op = o1;
    *(float4*)(op + 4) = o2;
}

extern "C" void kernel_launch(void* const* d_in, const int* in_sizes, int n_in,
                              void* d_out, int out_size, void* d_ws, size_t ws_size,
                              hipStream_t stream) {
    const float* X  = (const float*)d_in[0];
    const float* Wq = (const float*)d_in[1];
    const float* Wk = (const float*)d_in[2];
    const float* Wv = (const float*)d_in[3];
    unsigned short* ws = (unsigned short*)d_ws;
    const size_t SZ = (size_t)16384 * 64;
    unsigned short* Qhi  = ws;
    unsigned short* Qlo  = ws + SZ;
    unsigned short* Khi  = ws + 2 * SZ;
    unsigned short* Klo  = ws + 3 * SZ;
    unsigned short* Vthi = ws + 4 * SZ;
    unsigned short* Wthi = ws + 5 * SZ;
    unsigned short* Wtlo = Wthi + 192 * 1024;

    wprep_kernel<<<48, 256, 0, stream>>>(Wq, Wk, Wv, Wthi, Wtlo);
    qkv_kernel<<<dim3(512, 2), 256, 0, stream>>>(X, Wthi, Wtlo,
                                                 Qhi, Qlo, Khi, Klo, Vthi);
    attn_kernel<<<512, 256, 0, stream>>>(Qhi, Qlo, Khi, Klo, Vthi, (float*)d_out);
}

// Round 2
// 165.010 us; speedup vs baseline: 1.1055x; 1.1055x over previous
//
#include <hip/hip_runtime.h>

typedef float f32x4 __attribute__((ext_vector_type(4)));
typedef __bf16 bf16x8 __attribute__((ext_vector_type(8)));
typedef unsigned short us8 __attribute__((ext_vector_type(8)));
typedef unsigned short us4 __attribute__((ext_vector_type(4)));

#define QSCALE 11.541560327111707f   // 8 * log2(e) -> softmax in exp2 domain
#define NEG_INF (-__builtin_inff())

__device__ __forceinline__ float fexp2(float x) {
    return __builtin_amdgcn_exp2f(x);
}
__device__ __forceinline__ unsigned short f2bf(float x) {   // round-nearest
    unsigned u = __builtin_bit_cast(unsigned, x);
    u += 0x7fffu + ((u >> 16) & 1u);
    return (unsigned short)(u >> 16);
}
__device__ __forceinline__ float bf2f(unsigned short h) {
    unsigned u = ((unsigned)h) << 16;
    return __builtin_bit_cast(float, u);
}
__device__ __forceinline__ unsigned short bftrunc(float x) { // truncate
    return (unsigned short)(__builtin_bit_cast(unsigned, x) >> 16);
}
__device__ __forceinline__ f32x4 mfma16(us8 a, us8 b, f32x4 c) {
    return __builtin_amdgcn_mfma_f32_16x16x32_bf16(
        __builtin_bit_cast(bf16x8, a), __builtin_bit_cast(bf16x8, b), c, 0, 0, 0);
}
__device__ __forceinline__ void glds16(const unsigned short* g, unsigned short* l) {
    __builtin_amdgcn_global_load_lds(
        (const __attribute__((address_space(1))) unsigned int*)g,
        (__attribute__((address_space(3))) unsigned int*)l, 16, 0, 0);
}
// split 16 fp32 (4x float4) into hi/lo bf16 (trunc split)
__device__ __forceinline__ void split16(const float4* xv,
                                        us8& h0, us8& h1, us8& lo0, us8& lo1) {
    float xf[16];
#pragma unroll
    for (int i = 0; i < 4; ++i) {
        xf[4 * i] = xv[i].x; xf[4 * i + 1] = xv[i].y;
        xf[4 * i + 2] = xv[i].z; xf[4 * i + 3] = xv[i].w;
    }
#pragma unroll
    for (int e = 0; e < 8; ++e) {
        unsigned u0 = __builtin_bit_cast(unsigned, xf[e]);
        h0[e] = (unsigned short)(u0 >> 16);
        lo0[e] = bftrunc(xf[e] - __builtin_bit_cast(float, u0 & 0xffff0000u));
        unsigned u1 = __builtin_bit_cast(unsigned, xf[e + 8]);
        h1[e] = (unsigned short)(u1 >> 16);
        lo1[e] = bftrunc(xf[e + 8] - __builtin_bit_cast(float, u1 & 0xffff0000u));
    }
}

// ---------------- Kernel 0: W transpose + split (RN split) ----------------
__global__ __launch_bounds__(256) void wprep_kernel(
    const float* __restrict__ Wq, const float* __restrict__ Wk,
    const float* __restrict__ Wv,
    unsigned short* __restrict__ Wthi, unsigned short* __restrict__ Wtlo)
{
    __shared__ __align__(16) float Ls[64][68];
    const int g = blockIdx.x >> 4;
    const int k0 = (blockIdx.x & 15) << 6;
    const float* W = (g == 0) ? Wq : (g == 1) ? Wk : Wv;
    const int t = threadIdx.x;
#pragma unroll
    for (int u = 0; u < 4; ++u) {
        int idx = t + (u << 8);
        int row = idx >> 4, c4 = (idx & 15) << 2;
        *(float4*)&Ls[row][c4] = *(const float4*)&W[(size_t)(k0 + row) * 64 + c4];
    }
    __syncthreads();
    const int h = t >> 2, kk0 = (t & 3) << 4;
    size_t base = (size_t)((g << 6) + h) * 1024 + k0 + kk0;
#pragma unroll
    for (int c = 0; c < 4; ++c) {
        us4 hv, lv;
#pragma unroll
        for (int i = 0; i < 4; ++i) {
            float x = Ls[kk0 + (c << 2) + i][h];
            unsigned short hh = f2bf(x);
            hv[i] = hh;
            lv[i] = f2bf(x - bf2f(hh));
        }
        *(us4*)&Wthi[base + (c << 2)] = hv;
        *(us4*)&Wtlo[base + (c << 2)] = lv;
    }
}

// ---------------- Kernel 1: fused QKV projection ----------------
// v3: 64x96 tile, grid (256,2) = 2 blocks/CU. K-step 64.
// SINGLE barrier per K-step: X LDS (hi+lo) and W-hi LDS both double-buffered.
// glds W(k+1), X(k+1) reg-split + ds_write, X(k+2) global load are all issued
// at the TOP of iter k, so the structural vmcnt(0) drain before the one
// __syncthreads lands AFTER the 36-MFMA compute phase (latency hidden).
// W-lo: direct per-lane global frags (L1/L2). Q written pre-scaled.
__global__ __launch_bounds__(256, 2) void qkv_kernel(
    const float* __restrict__ X,
    const unsigned short* __restrict__ Wthi,
    const unsigned short* __restrict__ Wtlo,
    unsigned short* __restrict__ Qhi, unsigned short* __restrict__ Qlo,
    unsigned short* __restrict__ Khi, unsigned short* __restrict__ Klo,
    unsigned short* __restrict__ Vthi)
{
    __shared__ __align__(16) unsigned short sm[29952];  // 58.5 KB
    // [0,16384): X double buffer, stride 8192: hi at +0 (4096), lo at +4096
    unsigned short* Wh = sm + 16384;         // 2 buf x 6144 (96x64 swizzled)
    unsigned short* Vx = sm + 28672;         // 4x16x20 transpose scratch

    const int t = threadIdx.x;
    const int w = t >> 6, l = t & 63, lm = l & 15, lg = (l >> 4) & 3;
    const int wq = w >> 1, wc = w & 1;
    const int m0 = blockIdx.x << 6;
    const int y  = blockIdx.y;

    // --- W-hi glds staging: 3 x 1KB per wave per iter (8 rows each) ---
    const unsigned short* gsrc[3];
    int gdst[3];
#pragma unroll
    for (int i = 0; i < 3; ++i) {
        int g = w * 3 + i;                      // 0..11
        int n = (g << 3) + (l >> 3);            // W row 0..95
        int cg = (l & 7) ^ ((l >> 3) & 7);      // swizzled source chunk
        gsrc[i] = Wthi + (size_t)(y * 96 + n) * 1024 + (cg << 3);
        gdst[i] = g << 9;                       // g*512 us
    }
    // --- X staging: thread -> 16 floats (row t>>2, k (t&3)*16..+16) ---
    const int xrow = t >> 2;
    const int xc0 = (t & 3) << 1;
    const float* xptr = X + (size_t)(m0 + xrow) * 1024 + ((t & 3) << 4);
    const int xo_h0 = (xrow << 6) + ((xc0 ^ (xrow & 7)) << 3);
    const int xo_h1 = (xrow << 6) + (((xc0 | 1) ^ (xrow & 7)) << 3);

    // --- fragment LDS offsets (swizzle: slot = (kc*4+lg) ^ (lm&7)) ---
    int aoff[2][2], boff[3][2];
#pragma unroll
    for (int rt = 0; rt < 2; ++rt)
#pragma unroll
        for (int kc = 0; kc < 2; ++kc) {
            int m = (wq << 5) + (rt << 4) + lm;
            aoff[rt][kc] = (m << 6) + ((((kc << 2) + lg) ^ (lm & 7)) << 3);
        }
#pragma unroll
    for (int ct = 0; ct < 3; ++ct)
#pragma unroll
        for (int kc = 0; kc < 2; ++kc) {
            int n = wc * 48 + (ct << 4) + lm;
            boff[ct][kc] = (n << 6) + ((((kc << 2) + lg) ^ (lm & 7)) << 3);
        }
    // --- W-lo direct global fragment pointers ---
    const unsigned short* wlp[3][2];
#pragma unroll
    for (int ct = 0; ct < 3; ++ct)
#pragma unroll
        for (int kc = 0; kc < 2; ++kc)
            wlp[ct][kc] = Wtlo + (size_t)(y * 96 + wc * 48 + (ct << 4) + lm) * 1024
                               + (kc << 5) + (lg << 3);

    f32x4 acc[2][3];
#pragma unroll
    for (int i = 0; i < 2; ++i)
#pragma unroll
        for (int j = 0; j < 3; ++j) acc[i][j] = (f32x4){0.f, 0.f, 0.f, 0.f};

    // prologue: W(0) -> buf0; X(0) -> regs -> split -> xbuf0; X(1) -> regs
#pragma unroll
    for (int i = 0; i < 3; ++i) glds16(gsrc[i], Wh + gdst[i]);
    float4 xv[4];
#pragma unroll
    for (int i = 0; i < 4; ++i) xv[i] = *(const float4*)(xptr + (i << 2));
    {
        us8 h0, h1, lo0, lo1;
        split16(xv, h0, h1, lo0, lo1);
        *(us8*)&sm[xo_h0] = h0;        *(us8*)&sm[xo_h1] = h1;
        *(us8*)&sm[4096 + xo_h0] = lo0; *(us8*)&sm[4096 + xo_h1] = lo1;
    }
#pragma unroll
    for (int i = 0; i < 4; ++i) xv[i] = *(const float4*)(xptr + 64 + (i << 2));
    __syncthreads();

    for (int k = 0; k < 16; ++k) {
        const int xb = (k & 1) << 13;              // X buffer base (us)
        const int wb = (k & 1) * 6144;             // W buffer base (us)
        // ---- issue-early: everything for k+1/k+2, hidden under MFMA ----
        if (k < 15) {
            const int ko = (k + 1) << 6;
            const int nwb = 6144 - wb;
#pragma unroll
            for (int i = 0; i < 3; ++i) glds16(gsrc[i] + ko, Wh + nwb + gdst[i]);
            us8 h0, h1, lo0, lo1;
            split16(xv, h0, h1, lo0, lo1);         // X(k+1) reg-split
            const int nxb = 8192 - xb;
            *(us8*)&sm[nxb + xo_h0] = h0;          *(us8*)&sm[nxb + xo_h1] = h1;
            *(us8*)&sm[nxb + 4096 + xo_h0] = lo0;  *(us8*)&sm[nxb + 4096 + xo_h1] = lo1;
            if (k < 14) {
                const int ko2 = (k + 2) << 6;
#pragma unroll
                for (int i = 0; i < 4; ++i)
                    xv[i] = *(const float4*)(xptr + ko2 + (i << 2));
            }
        }
        // ---- compute phase: W-lo globals + LDS frags + 36 MFMA ----
        us8 bl[3][2];
#pragma unroll
        for (int ct = 0; ct < 3; ++ct)
#pragma unroll
            for (int kc = 0; kc < 2; ++kc)
                bl[ct][kc] = *(const us8*)(wlp[ct][kc] + (k << 6));
        us8 ah[2][2], al[2][2], bh[3][2];
#pragma unroll
        for (int rt = 0; rt < 2; ++rt)
#pragma unroll
            for (int kc = 0; kc < 2; ++kc) {
                ah[rt][kc] = *(const us8*)&sm[xb + aoff[rt][kc]];
                al[rt][kc] = *(const us8*)&sm[xb + 4096 + aoff[rt][kc]];
            }
#pragma unroll
        for (int ct = 0; ct < 3; ++ct)
#pragma unroll
            for (int kc = 0; kc < 2; ++kc)
                bh[ct][kc] = *(const us8*)&Wh[wb + boff[ct][kc]];
        // LDS-only terms first (hi*hi, lo*hi), then terms needing W-lo globals
#pragma unroll
        for (int kc = 0; kc < 2; ++kc)
#pragma unroll
            for (int rt = 0; rt < 2; ++rt)
#pragma unroll
                for (int ct = 0; ct < 3; ++ct) {
                    acc[rt][ct] = mfma16(ah[rt][kc], bh[ct][kc], acc[rt][ct]);
                    acc[rt][ct] = mfma16(al[rt][kc], bh[ct][kc], acc[rt][ct]);
                }
#pragma unroll
        for (int kc = 0; kc < 2; ++kc)
#pragma unroll
            for (int rt = 0; rt < 2; ++rt)
#pragma unroll
                for (int ct = 0; ct < 3; ++ct)
                    acc[rt][ct] = mfma16(ah[rt][kc], bl[ct][kc], acc[rt][ct]);
        __syncthreads();                           // ONE barrier per K-step
    }

    // epilogue: trunc-split stores; Q pre-scaled; V transposed via Vx
    const int tbr = m0 + (wq << 5);
#pragma unroll
    for (int rt = 0; rt < 2; ++rt) {
#pragma unroll
        for (int ct = 0; ct < 3; ++ct) {
            const int gc = y * 96 + wc * 48 + (ct << 4);
            if (gc < 128) {
                unsigned short* Dh = (gc < 64) ? Qhi : Khi;
                unsigned short* Dl = (gc < 64) ? Qlo : Klo;
                const float sc = (gc < 64) ? QSCALE : 1.0f;
                const int colb = (gc & 63) + lm;
#pragma unroll
                for (int r = 0; r < 4; ++r) {
                    int row = tbr + (rt << 4) + (lg << 2) + r;
                    float x = acc[rt][ct][r] * sc;
                    unsigned u = __builtin_bit_cast(unsigned, x);
                    size_t o = (size_t)row * 64 + colb;
                    Dh[o] = (unsigned short)(u >> 16);
                    Dl[o] = bftrunc(x - __builtin_bit_cast(float, u & 0xffff0000u));
                }
            } else {
                // V: 16x16 transpose via wave-local LDS
#pragma unroll
                for (int r = 0; r < 4; ++r)
                    Vx[w * 320 + lm * 20 + (lg << 2) + r] = bftrunc(acc[rt][ct][r]);
                __asm__ volatile("" ::: "memory");
                const int h0 = gc - 128;
                const int tb = tbr + (rt << 4);
                const int bb = tb >> 11;
                const int tl = (tb & 2047) + ((l & 3) << 2);
                const int hh2 = h0 + (l >> 2);
                us4 vv = *(const us4*)&Vx[w * 320 + (l >> 2) * 20 + ((l & 3) << 2)];
                *(us4*)&Vthi[(size_t)((bb << 6) + hh2) * 2048 + tl] = vv;
                __asm__ volatile("" ::: "memory");
            }
        }
    }
}

// ---------------- Kernel 2: causal flash attention ----------------
// 512 blocks = (b, 32-row q-tile, heavy-first). 4 waves = 4 key-parities,
// ZERO barriers in the K-loop (K/V frags direct from global, L2-resident).
// S^T layout: lane = q-row -> softmax reduce = 15 local ops + 2 shuffles.
// exp2 domain (Q pre-scaled by 8*log2e). 4-way merge at end.
__global__ __launch_bounds__(256, 2) void attn_kernel(
    const unsigned short* __restrict__ Qhi, const unsigned short* __restrict__ Qlo,
    const unsigned short* __restrict__ Khi, const unsigned short* __restrict__ Klo,
    const unsigned short* __restrict__ Vthi,
    float* __restrict__ O)
{
    __shared__ __align__(16) unsigned char smem[33792];
    unsigned short* PS = (unsigned short*)smem;     // [4][32][72] us (loop phase)
    float* FO = (float*)smem;                       // [4][32][64] f32 (merge phase)
    float* FM = (float*)(smem + 32768);             // [4][32]
    float* FL = FM + 128;

    const int t = threadIdx.x;
    const int w = t >> 6, l = t & 63, lm = l & 15, lg = (l >> 4) & 3;
    const int b = blockIdx.x & 7;
    const int qp = 63 - (blockIdx.x >> 3);          // heavy tiles first
    const int nk = (qp >> 1) + 1;                   // 64-key tiles needed
    const int q0 = qp << 5;
    const size_t brow = (size_t)b << 11;

    // Q fragments pinned (B-operand: lane=qrow, k=lg*8+j)
    us8 qh[2][2], ql[2][2];
#pragma unroll
    for (int nt = 0; nt < 2; ++nt)
#pragma unroll
        for (int kc = 0; kc < 2; ++kc) {
            size_t off = (brow + q0 + (nt << 4) + lm) * 64 + (kc << 5) + (lg << 3);
            qh[nt][kc] = *(const us8*)&Qhi[off];
            ql[nt][kc] = *(const us8*)&Qlo[off];
        }

    f32x4 o_acc[2][4];
#pragma unroll
    for (int nt = 0; nt < 2; ++nt)
#pragma unroll
        for (int ct = 0; ct < 4; ++ct) o_acc[nt][ct] = (f32x4){0.f, 0.f, 0.f, 0.f};
    float m_r[2] = {NEG_INF, NEG_INF}, l_r[2] = {0.f, 0.f};
    unsigned short* ps = PS + w * 2304;             // wave-local 32x72

    for (int j = w; j < nk; j += 4) {
        const int kk0 = j << 6;
        us8 kh[4][2], klo[4][2], vh[4][2];
#pragma unroll
        for (int mt = 0; mt < 4; ++mt)
#pragma unroll
            for (int kc = 0; kc < 2; ++kc) {
                size_t off = (brow + kk0 + (mt << 4) + lm) * 64 + (kc << 5) + (lg << 3);
                kh[mt][kc] = *(const us8*)&Khi[off];
                klo[mt][kc] = *(const us8*)&Klo[off];
            }
#pragma unroll
        for (int ct = 0; ct < 4; ++ct)
#pragma unroll
            for (int kc = 0; kc < 2; ++kc) {
                size_t off = ((size_t)(b << 6) + (ct << 4) + lm) * 2048
                           + kk0 + (kc << 5) + (lg << 3);
                vh[ct][kc] = *(const us8*)&Vthi[off];
            }
        // S^T = K Q^T (split-bf16)
        f32x4 s[4][2];
#pragma unroll
        for (int mt = 0; mt < 4; ++mt)
#pragma unroll
            for (int nt = 0; nt < 2; ++nt) s[mt][nt] = (f32x4){0.f, 0.f, 0.f, 0.f};
#pragma unroll
        for (int kc = 0; kc < 2; ++kc)
#pragma unroll
            for (int mt = 0; mt < 4; ++mt)
#pragma unroll
                for (int nt = 0; nt < 2; ++nt) {
                    s[mt][nt] = mfma16(kh[mt][kc], qh[nt][kc], s[mt][nt]);
                    s[mt][nt] = mfma16(klo[mt][kc], qh[nt][kc], s[mt][nt]);
                    s[mt][nt] = mfma16(kh[mt][kc], ql[nt][kc], s[mt][nt]);
                }
        // online softmax (exp2 domain), lane owns row q0+nt*16+lm, 16 keys
        float alz[2];
#pragma unroll
        for (int nt = 0; nt < 2; ++nt) {
            const int qr = q0 + (nt << 4) + lm;
            float sv[16];
            if ((kk0 + 63) <= (q0 + (nt << 4))) {
#pragma unroll
                for (int mt = 0; mt < 4; ++mt)
#pragma unroll
                    for (int r = 0; r < 4; ++r) sv[(mt << 2) + r] = s[mt][nt][r];
            } else {
#pragma unroll
                for (int mt = 0; mt < 4; ++mt)
#pragma unroll
                    for (int r = 0; r < 4; ++r) {
                        const int key = kk0 + (mt << 4) + (lg << 2) + r;
                        sv[(mt << 2) + r] = (key <= qr) ? s[mt][nt][r] : NEG_INF;
                    }
            }
            float t8[8];
#pragma unroll
            for (int i = 0; i < 8; ++i) t8[i] = fmaxf(sv[i], sv[i + 8]);
#pragma unroll
            for (int i = 0; i < 4; ++i) t8[i] = fmaxf(t8[i], t8[i + 4]);
            float mx = fmaxf(fmaxf(t8[0], t8[1]), fmaxf(t8[2], t8[3]));
            mx = fmaxf(mx, __shfl_xor(mx, 16));
            mx = fmaxf(mx, __shfl_xor(mx, 32));
            const float mn = fmaxf(m_r[nt], mx);
            alz[nt] = fexp2(m_r[nt] - mn);
            m_r[nt] = mn;
            float p[16];
#pragma unroll
            for (int i = 0; i < 16; ++i) p[i] = fexp2(sv[i] - mn);
#pragma unroll
            for (int mt = 0; mt < 4; ++mt) {
                us4 pk;
#pragma unroll
                for (int r = 0; r < 4; ++r) pk[r] = bftrunc(p[(mt << 2) + r]);
                *(us4*)&ps[((nt << 4) + lm) * 72 + (mt << 4) + (lg << 2)] = pk;
            }
            float s8[8];
#pragma unroll
            for (int i = 0; i < 8; ++i) s8[i] = p[i] + p[i + 8];
#pragma unroll
            for (int i = 0; i < 4; ++i) s8[i] = s8[i] + s8[i + 4];
            float rs = (s8[0] + s8[1]) + (s8[2] + s8[3]);
            rs += __shfl_xor(rs, 16);
            rs += __shfl_xor(rs, 32);
            l_r[nt] = l_r[nt] * alz[nt] + rs;
        }
        __asm__ volatile("" ::: "memory");   // P write -> read, same wave
        // rescale O (alz lives at lane=row; fetch via shuffle)
#pragma unroll
        for (int nt = 0; nt < 2; ++nt)
#pragma unroll
            for (int r = 0; r < 4; ++r) {
                const float av = __shfl(alz[nt], (lg << 2) + r);
#pragma unroll
                for (int ct = 0; ct < 4; ++ct) o_acc[nt][ct][r] *= av;
            }
        // O += P V
#pragma unroll
        for (int nt = 0; nt < 2; ++nt)
#pragma unroll
            for (int kc = 0; kc < 2; ++kc) {
                us8 pa = *(const us8*)&ps[((nt << 4) + lm) * 72 + (kc << 5) + (lg << 3)];
#pragma unroll
                for (int ct = 0; ct < 4; ++ct)
                    o_acc[nt][ct] = mfma16(pa, vh[ct][kc], o_acc[nt][ct]);
            }
    }

    // ---- 4-way key-parity merge ----
    __syncthreads();                         // all PS use done before FO alias
#pragma unroll
    for (int nt = 0; nt < 2; ++nt)
#pragma unroll
        for (int ct = 0; ct < 4; ++ct)
#pragma unroll
            for (int r = 0; r < 4; ++r)
                FO[(w << 11) + (((nt << 4) + (lg << 2) + r) << 6) + (ct << 4) + lm]
                    = o_acc[nt][ct][r];
    if (l < 16) {
        FM[(w << 5) + lm] = m_r[0]; FM[(w << 5) + 16 + lm] = m_r[1];
        FL[(w << 5) + lm] = l_r[0]; FL[(w << 5) + 16 + lm] = l_r[1];
    }
    __syncthreads();
    const int jr = t >> 3;                   // row 0..31
    const int cg = (t & 7) << 3;             // col base
    float m0v = FM[jr], m1v = FM[32 + jr], m2v = FM[64 + jr], m3v = FM[96 + jr];
    float mm = fmaxf(fmaxf(m0v, m1v), fmaxf(m2v, m3v));
    float a0 = fexp2(m0v - mm), a1 = fexp2(m1v - mm);
    float a2 = fexp2(m2v - mm), a3 = fexp2(m3v - mm);
    float L = a0 * FL[jr] + a1 * FL[32 + jr] + a2 * FL[64 + jr] + a3 * FL[96 + jr];
    float inv = 1.0f / L;
    float ov[8];
#pragma unroll
    for (int c = 0; c < 8; ++c)
        ov[c] = a0 * FO[(jr << 6) + cg + c] + a1 * FO[2048 + (jr << 6) + cg + c]
              + a2 * FO[4096 + (jr << 6) + cg + c] + a3 * FO[6144 + (jr << 6) + cg + c];
    float4 o1 = {ov[0] * inv, ov[1] * inv, ov[2] * inv, ov[3] * inv};
    float4 o2 = {ov[4] * inv, ov[5] * inv, ov[6] * inv, ov[7] * inv};
    float* op = O + (brow + q0 + jr) * 64 + cg;
    *(float4*)op = o1;
    *(float4*)(op + 4) = o2;
}

extern "C" void kernel_launch(void* const* d_in, const int* in_sizes, int n_in,
                              void* d_out, int out_size, void* d_ws, size_t ws_size,
                              hipStream_t stream) {
    const float* X  = (const float*)d_in[0];
    const float* Wq = (const float*)d_in[1];
    const float* Wk = (const float*)d_in[2];
    const float* Wv = (const float*)d_in[3];
    unsigned short* ws = (unsigned short*)d_ws;
    const size_t SZ = (size_t)16384 * 64;
    unsigned short* Qhi  = ws;
    unsigned short* Qlo  = ws + SZ;
    unsigned short* Khi  = ws + 2 * SZ;
    unsigned short* Klo  = ws + 3 * SZ;
    unsigned short* Vthi = ws + 4 * SZ;
    unsigned short* Wthi = ws + 5 * SZ;
    unsigned short* Wtlo = Wthi + 192 * 1024;

    wprep_kernel<<<48, 256, 0, stream>>>(Wq, Wk, Wv, Wthi, Wtlo);
    qkv_kernel<<<dim3(256, 2), 256, 0, stream>>>(X, Wthi, Wtlo,
                                                 Qhi, Qlo, Khi, Klo, Vthi);
    attn_kernel<<<512, 256, 0, stream>>>(Qhi, Qlo, Khi, Klo, Vthi, (float*)d_out);
}

// Round 3
// 161.615 us; speedup vs baseline: 1.1287x; 1.0210x over previous
//
#include <hip/hip_runtime.h>

typedef float f32x4 __attribute__((ext_vector_type(4)));
typedef __bf16 bf16x8 __attribute__((ext_vector_type(8)));
typedef unsigned short us8 __attribute__((ext_vector_type(8)));
typedef unsigned short us4 __attribute__((ext_vector_type(4)));

#define QSCALE 11.541560327111707f   // 8 * log2(e) -> softmax in exp2 domain
#define NEG_INF (-__builtin_inff())

__device__ __forceinline__ float fexp2(float x) {
    return __builtin_amdgcn_exp2f(x);
}
__device__ __forceinline__ unsigned short f2bf(float x) {   // round-nearest
    unsigned u = __builtin_bit_cast(unsigned, x);
    u += 0x7fffu + ((u >> 16) & 1u);
    return (unsigned short)(u >> 16);
}
__device__ __forceinline__ float bf2f(unsigned short h) {
    unsigned u = ((unsigned)h) << 16;
    return __builtin_bit_cast(float, u);
}
__device__ __forceinline__ unsigned short bftrunc(float x) { // truncate
    return (unsigned short)(__builtin_bit_cast(unsigned, x) >> 16);
}
__device__ __forceinline__ f32x4 mfma16(us8 a, us8 b, f32x4 c) {
    return __builtin_amdgcn_mfma_f32_16x16x32_bf16(
        __builtin_bit_cast(bf16x8, a), __builtin_bit_cast(bf16x8, b), c, 0, 0, 0);
}
__device__ __forceinline__ void glds16(const unsigned short* g, unsigned short* l) {
    __builtin_amdgcn_global_load_lds(
        (const __attribute__((address_space(1))) unsigned int*)g,
        (__attribute__((address_space(3))) unsigned int*)l, 16, 0, 0);
}
// split 8 fp32 (2x float4) into hi/lo bf16 (trunc split)
__device__ __forceinline__ void splitx(float4 a, float4 b, us8& h, us8& lo) {
    float xf[8] = {a.x, a.y, a.z, a.w, b.x, b.y, b.z, b.w};
#pragma unroll
    for (int e = 0; e < 8; ++e) {
        unsigned u = __builtin_bit_cast(unsigned, xf[e]);
        h[e] = (unsigned short)(u >> 16);
        lo[e] = bftrunc(xf[e] - __builtin_bit_cast(float, u & 0xffff0000u));
    }
}

// ---------------- Kernel 0: W transpose + split (RN split) ----------------
__global__ __launch_bounds__(256) void wprep_kernel(
    const float* __restrict__ Wq, const float* __restrict__ Wk,
    const float* __restrict__ Wv,
    unsigned short* __restrict__ Wthi, unsigned short* __restrict__ Wtlo)
{
    __shared__ __align__(16) float Ls[64][68];
    const int g = blockIdx.x >> 4;
    const int k0 = (blockIdx.x & 15) << 6;
    const float* W = (g == 0) ? Wq : (g == 1) ? Wk : Wv;
    const int t = threadIdx.x;
#pragma unroll
    for (int u = 0; u < 4; ++u) {
        int idx = t + (u << 8);
        int row = idx >> 4, c4 = (idx & 15) << 2;
        *(float4*)&Ls[row][c4] = *(const float4*)&W[(size_t)(k0 + row) * 64 + c4];
    }
    __syncthreads();
    const int h = t >> 2, kk0 = (t & 3) << 4;
    size_t base = (size_t)((g << 6) + h) * 1024 + k0 + kk0;
#pragma unroll
    for (int c = 0; c < 4; ++c) {
        us4 hv, lv;
#pragma unroll
        for (int i = 0; i < 4; ++i) {
            float x = Ls[kk0 + (c << 2) + i][h];
            unsigned short hh = f2bf(x);
            hv[i] = hh;
            lv[i] = f2bf(x - bf2f(hh));
        }
        *(us4*)&Wthi[base + (c << 2)] = hv;
        *(us4*)&Wtlo[base + (c << 2)] = lv;
    }
}

// ---------------- Kernel 1: fused QKV projection ----------------
// v4: 64x96 tile, grid (256,2) = 2 blocks/CU. K-step 64.
// NO X LDS staging: each wave owns 16 UNIQUE rows x 96 cols; the MFMA
// A-fragment is 8 contiguous fp32 per lane, loaded DIRECTLY from global
// (2x float4 per kc), trunc-split in registers during the MFMA phase.
// W-hi AND W-lo both glds-staged, double-buffered (6 glds/wave/iter) ->
// all 36 MFMAs run back-to-back on reg/LDS operands, no mid-stream vmcnt.
// One __syncthreads per K-step; everything issued early so drains are covered.
__global__ __launch_bounds__(256, 2) void qkv_kernel(
    const float* __restrict__ X,
    const unsigned short* __restrict__ Wthi,
    const unsigned short* __restrict__ Wtlo,
    unsigned short* __restrict__ Qhi, unsigned short* __restrict__ Qlo,
    unsigned short* __restrict__ Khi, unsigned short* __restrict__ Klo,
    unsigned short* __restrict__ Vthi)
{
    __shared__ __align__(16) unsigned short sm[25856];  // 50.5 KB
    unsigned short* Wh = sm;              // 2 buf x 12288 us: [hi 6144 | lo 6144]
    unsigned short* Vx = sm + 24576;      // 4x16x20 transpose scratch

    const int t = threadIdx.x;
    const int w = t >> 6, l = t & 63, lm = l & 15, lg = (l >> 4) & 3;
    const int m0 = blockIdx.x << 6;
    const int y  = blockIdx.y;

    // --- W glds staging: per wave 3 hi + 3 lo chunks (8 rows each, 1KB) ---
    size_t woff[3];
    int gdst[3];
#pragma unroll
    for (int i = 0; i < 3; ++i) {
        int g = w * 3 + i;                      // 0..11
        int n = (g << 3) + (l >> 3);            // W row 0..95
        int cg = (l & 7) ^ ((l >> 3) & 7);      // swizzled source chunk
        woff[i] = (size_t)(y * 96 + n) * 1024 + (cg << 3);
        gdst[i] = g << 9;                       // g*512 us
    }
    // --- X direct per-lane fragment pointer (wave owns rows w*16..w*16+16) ---
    const float* xptr = X + (size_t)(m0 + (w << 4) + lm) * 1024 + (lg << 3);

    // --- W fragment LDS offsets (swizzle: slot = (kc*4+lg) ^ (lm&7)) ---
    int boff[6][2];
#pragma unroll
    for (int ct = 0; ct < 6; ++ct)
#pragma unroll
        for (int kc = 0; kc < 2; ++kc) {
            int n = (ct << 4) + lm;
            boff[ct][kc] = (n << 6) + ((((kc << 2) + lg) ^ (lm & 7)) << 3);
        }

    f32x4 acc[6];
#pragma unroll
    for (int j = 0; j < 6; ++j) acc[j] = (f32x4){0.f, 0.f, 0.f, 0.f};

    // prologue: W(0) hi+lo -> buf0; X(0) -> regs -> split
#pragma unroll
    for (int i = 0; i < 3; ++i) glds16(Wthi + woff[i], Wh + gdst[i]);
#pragma unroll
    for (int i = 0; i < 3; ++i) glds16(Wtlo + woff[i], Wh + 6144 + gdst[i]);
    float4 xv0 = *(const float4*)(xptr);
    float4 xv1 = *(const float4*)(xptr + 4);
    float4 xv2 = *(const float4*)(xptr + 32);
    float4 xv3 = *(const float4*)(xptr + 36);
    us8 ahc[2], alc[2];
    splitx(xv0, xv1, ahc[0], alc[0]);
    splitx(xv2, xv3, ahc[1], alc[1]);
    __syncthreads();                            // buf0 visible

    for (int k = 0; k < 16; ++k) {
        const int wb = (k & 1) * 12288;
        // ---- issue-early: W(k+1) glds + X(k+1) loads, hidden under MFMA ----
        if (k < 15) {
            const int nwb = 12288 - wb;
            const size_t ko = (size_t)(k + 1) << 6;
#pragma unroll
            for (int i = 0; i < 3; ++i)
                glds16(Wthi + woff[i] + ko, Wh + nwb + gdst[i]);
#pragma unroll
            for (int i = 0; i < 3; ++i)
                glds16(Wtlo + woff[i] + ko, Wh + nwb + 6144 + gdst[i]);
            const int kg = (k + 1) << 6;
            xv0 = *(const float4*)(xptr + kg);
            xv1 = *(const float4*)(xptr + kg + 4);
            xv2 = *(const float4*)(xptr + kg + 32);
            xv3 = *(const float4*)(xptr + kg + 36);
        }
        // ---- compute: 12 ds_read_b128 + 36 MFMA, all reg/LDS operands ----
        us8 bh[6][2], bl[6][2];
#pragma unroll
        for (int ct = 0; ct < 6; ++ct)
#pragma unroll
            for (int kc = 0; kc < 2; ++kc) {
                bh[ct][kc] = *(const us8*)&Wh[wb + boff[ct][kc]];
                bl[ct][kc] = *(const us8*)&Wh[wb + 6144 + boff[ct][kc]];
            }
#pragma unroll
        for (int kc = 0; kc < 2; ++kc)
#pragma unroll
            for (int ct = 0; ct < 6; ++ct) {
                acc[ct] = mfma16(ahc[kc], bh[ct][kc], acc[ct]);
                acc[ct] = mfma16(alc[kc], bh[ct][kc], acc[ct]);
                acc[ct] = mfma16(ahc[kc], bl[ct][kc], acc[ct]);
            }
        // ---- convert X(k+1) in regs (vmcnt wait covered by MFMA phase) ----
        if (k < 15) {
            splitx(xv0, xv1, ahc[0], alc[0]);
            splitx(xv2, xv3, ahc[1], alc[1]);
        }
        __syncthreads();                        // ONE barrier per K-step
    }

    // epilogue: trunc-split stores; Q pre-scaled; V transposed via Vx
    const int tbr = m0 + (w << 4);
#pragma unroll
    for (int ct = 0; ct < 6; ++ct) {
        const int gc = y * 96 + (ct << 4);
        if (gc < 128) {
            unsigned short* Dh = (gc < 64) ? Qhi : Khi;
            unsigned short* Dl = (gc < 64) ? Qlo : Klo;
            const float sc = (gc < 64) ? QSCALE : 1.0f;
            const int colb = (gc & 63) + lm;
#pragma unroll
            for (int r = 0; r < 4; ++r) {
                int row = tbr + (lg << 2) + r;
                float x = acc[ct][r] * sc;
                unsigned u = __builtin_bit_cast(unsigned, x);
                size_t o = (size_t)row * 64 + colb;
                Dh[o] = (unsigned short)(u >> 16);
                Dl[o] = bftrunc(x - __builtin_bit_cast(float, u & 0xffff0000u));
            }
        } else {
            // V: 16x16 transpose via wave-local LDS
#pragma unroll
            for (int r = 0; r < 4; ++r)
                Vx[w * 320 + lm * 20 + (lg << 2) + r] = bftrunc(acc[ct][r]);
            __asm__ volatile("" ::: "memory");
            const int h0 = gc - 128;
            const int tb = tbr;
            const int bb = tb >> 11;
            const int tl = (tb & 2047) + ((l & 3) << 2);
            const int hh2 = h0 + (l >> 2);
            us4 vv = *(const us4*)&Vx[w * 320 + (l >> 2) * 20 + ((l & 3) << 2)];
            *(us4*)&Vthi[(size_t)((bb << 6) + hh2) * 2048 + tl] = vv;
            __asm__ volatile("" ::: "memory");
        }
    }
}

// ---------------- Kernel 2: causal flash attention ----------------
// 512 blocks = (b, 32-row q-tile, heavy-first). 4 waves = 4 key-parities,
// ZERO barriers in the K-loop (K/V frags direct from global, L2-resident).
// S^T layout: lane = q-row -> softmax reduce = 15 local ops + 2 shuffles.
// exp2 domain (Q pre-scaled by 8*log2e). 4-way merge at end.
__global__ __launch_bounds__(256, 2) void attn_kernel(
    const unsigned short* __restrict__ Qhi, const unsigned short* __restrict__ Qlo,
    const unsigned short* __restrict__ Khi, const unsigned short* __restrict__ Klo,
    const unsigned short* __restrict__ Vthi,
    float* __restrict__ O)
{
    __shared__ __align__(16) unsigned char smem[33792];
    unsigned short* PS = (unsigned short*)smem;     // [4][32][72] us (loop phase)
    float* FO = (float*)smem;                       // [4][32][64] f32 (merge phase)
    float* FM = (float*)(smem + 32768);             // [4][32]
    float* FL = FM + 128;

    const int t = threadIdx.x;
    const int w = t >> 6, l = t & 63, lm = l & 15, lg = (l >> 4) & 3;
    const int b = blockIdx.x & 7;
    const int qp = 63 - (blockIdx.x >> 3);          // heavy tiles first
    const int nk = (qp >> 1) + 1;                   // 64-key tiles needed
    const int q0 = qp << 5;
    const size_t brow = (size_t)b << 11;

    // Q fragments pinned (B-operand: lane=qrow, k=lg*8+j)
    us8 qh[2][2], ql[2][2];
#pragma unroll
    for (int nt = 0; nt < 2; ++nt)
#pragma unroll
        for (int kc = 0; kc < 2; ++kc) {
            size_t off = (brow + q0 + (nt << 4) + lm) * 64 + (kc << 5) + (lg << 3);
            qh[nt][kc] = *(const us8*)&Qhi[off];
            ql[nt][kc] = *(const us8*)&Qlo[off];
        }

    f32x4 o_acc[2][4];
#pragma unroll
    for (int nt = 0; nt < 2; ++nt)
#pragma unroll
        for (int ct = 0; ct < 4; ++ct) o_acc[nt][ct] = (f32x4){0.f, 0.f, 0.f, 0.f};
    float m_r[2] = {NEG_INF, NEG_INF}, l_r[2] = {0.f, 0.f};
    unsigned short* ps = PS + w * 2304;             // wave-local 32x72

    for (int j = w; j < nk; j += 4) {
        const int kk0 = j << 6;
        us8 kh[4][2], klo[4][2], vh[4][2];
#pragma unroll
        for (int mt = 0; mt < 4; ++mt)
#pragma unroll
            for (int kc = 0; kc < 2; ++kc) {
                size_t off = (brow + kk0 + (mt << 4) + lm) * 64 + (kc << 5) + (lg << 3);
                kh[mt][kc] = *(const us8*)&Khi[off];
                klo[mt][kc] = *(const us8*)&Klo[off];
            }
#pragma unroll
        for (int ct = 0; ct < 4; ++ct)
#pragma unroll
            for (int kc = 0; kc < 2; ++kc) {
                size_t off = ((size_t)(b << 6) + (ct << 4) + lm) * 2048
                           + kk0 + (kc << 5) + (lg << 3);
                vh[ct][kc] = *(const us8*)&Vthi[off];
            }
        // S^T = K Q^T (split-bf16)
        f32x4 s[4][2];
#pragma unroll
        for (int mt = 0; mt < 4; ++mt)
#pragma unroll
            for (int nt = 0; nt < 2; ++nt) s[mt][nt] = (f32x4){0.f, 0.f, 0.f, 0.f};
#pragma unroll
        for (int kc = 0; kc < 2; ++kc)
#pragma unroll
            for (int mt = 0; mt < 4; ++mt)
#pragma unroll
                for (int nt = 0; nt < 2; ++nt) {
                    s[mt][nt] = mfma16(kh[mt][kc], qh[nt][kc], s[mt][nt]);
                    s[mt][nt] = mfma16(klo[mt][kc], qh[nt][kc], s[mt][nt]);
                    s[mt][nt] = mfma16(kh[mt][kc], ql[nt][kc], s[mt][nt]);
                }
        // online softmax (exp2 domain), lane owns row q0+nt*16+lm, 16 keys
        float alz[2];
#pragma unroll
        for (int nt = 0; nt < 2; ++nt) {
            const int qr = q0 + (nt << 4) + lm;
            float sv[16];
            if ((kk0 + 63) <= (q0 + (nt << 4))) {
#pragma unroll
                for (int mt = 0; mt < 4; ++mt)
#pragma unroll
                    for (int r = 0; r < 4; ++r) sv[(mt << 2) + r] = s[mt][nt][r];
            } else {
#pragma unroll
                for (int mt = 0; mt < 4; ++mt)
#pragma unroll
                    for (int r = 0; r < 4; ++r) {
                        const int key = kk0 + (mt << 4) + (lg << 2) + r;
                        sv[(mt << 2) + r] = (key <= qr) ? s[mt][nt][r] : NEG_INF;
                    }
            }
            float t8[8];
#pragma unroll
            for (int i = 0; i < 8; ++i) t8[i] = fmaxf(sv[i], sv[i + 8]);
#pragma unroll
            for (int i = 0; i < 4; ++i) t8[i] = fmaxf(t8[i], t8[i + 4]);
            float mx = fmaxf(fmaxf(t8[0], t8[1]), fmaxf(t8[2], t8[3]));
            mx = fmaxf(mx, __shfl_xor(mx, 16));
            mx = fmaxf(mx, __shfl_xor(mx, 32));
            const float mn = fmaxf(m_r[nt], mx);
            alz[nt] = fexp2(m_r[nt] - mn);
            m_r[nt] = mn;
            float p[16];
#pragma unroll
            for (int i = 0; i < 16; ++i) p[i] = fexp2(sv[i] - mn);
#pragma unroll
            for (int mt = 0; mt < 4; ++mt) {
                us4 pk;
#pragma unroll
                for (int r = 0; r < 4; ++r) pk[r] = bftrunc(p[(mt << 2) + r]);
                *(us4*)&ps[((nt << 4) + lm) * 72 + (mt << 4) + (lg << 2)] = pk;
            }
            float s8[8];
#pragma unroll
            for (int i = 0; i < 8; ++i) s8[i] = p[i] + p[i + 8];
#pragma unroll
            for (int i = 0; i < 4; ++i) s8[i] = s8[i] + s8[i + 4];
            float rs = (s8[0] + s8[1]) + (s8[2] + s8[3]);
            rs += __shfl_xor(rs, 16);
            rs += __shfl_xor(rs, 32);
            l_r[nt] = l_r[nt] * alz[nt] + rs;
        }
        __asm__ volatile("" ::: "memory");   // P write -> read, same wave
        // rescale O (alz lives at lane=row; fetch via shuffle)
#pragma unroll
        for (int nt = 0; nt < 2; ++nt)
#pragma unroll
            for (int r = 0; r < 4; ++r) {
                const float av = __shfl(alz[nt], (lg << 2) + r);
#pragma unroll
                for (int ct = 0; ct < 4; ++ct) o_acc[nt][ct][r] *= av;
            }
        // O += P V
#pragma unroll
        for (int nt = 0; nt < 2; ++nt)
#pragma unroll
            for (int kc = 0; kc < 2; ++kc) {
                us8 pa = *(const us8*)&ps[((nt << 4) + lm) * 72 + (kc << 5) + (lg << 3)];
#pragma unroll
                for (int ct = 0; ct < 4; ++ct)
                    o_acc[nt][ct] = mfma16(pa, vh[ct][kc], o_acc[nt][ct]);
            }
    }

    // ---- 4-way key-parity merge ----
    __syncthreads();                         // all PS use done before FO alias
#pragma unroll
    for (int nt = 0; nt < 2; ++nt)
#pragma unroll
        for (int ct = 0; ct < 4; ++ct)
#pragma unroll
            for (int r = 0; r < 4; ++r)
                FO[(w << 11) + (((nt << 4) + (lg << 2) + r) << 6) + (ct << 4) + lm]
                    = o_acc[nt][ct][r];
    if (l < 16) {
        FM[(w << 5) + lm] = m_r[0]; FM[(w << 5) + 16 + lm] = m_r[1];
        FL[(w << 5) + lm] = l_r[0]; FL[(w << 5) + 16 + lm] = l_r[1];
    }
    __syncthreads();
    const int jr = t >> 3;                   // row 0..31
    const int cg = (t & 7) << 3;             // col base
    float m0v = FM[jr], m1v = FM[32 + jr], m2v = FM[64 + jr], m3v = FM[96 + jr];
    float mm = fmaxf(fmaxf(m0v, m1v), fmaxf(m2v, m3v));
    float a0 = fexp2(m0v - mm), a1 = fexp2(m1v - mm);
    float a2 = fexp2(m2v - mm), a3 = fexp2(m3v - mm);
    float L = a0 * FL[jr] + a1 * FL[32 + jr] + a2 * FL[64 + jr] + a3 * FL[96 + jr];
    float inv = 1.0f / L;
    float ov[8];
#pragma unroll
    for (int c = 0; c < 8; ++c)
        ov[c] = a0 * FO[(jr << 6) + cg + c] + a1 * FO[2048 + (jr << 6) + cg + c]
              + a2 * FO[4096 + (jr << 6) + cg + c] + a3 * FO[6144 + (jr << 6) + cg + c];
    float4 o1 = {ov[0] * inv, ov[1] * inv, ov[2] * inv, ov[3] * inv};
    float4 o2 = {ov[4] * inv, ov[5] * inv, ov[6] * inv, ov[7] * inv};
    float* op = O + (brow + q0 + jr) * 64 + cg;
    *(float4*)op = o1;
    *(float4*)(op + 4) = o2;
}

extern "C" void kernel_launch(void* const* d_in, const int* in_sizes, int n_in,
                              void* d_out, int out_size, void* d_ws, size_t ws_size,
                              hipStream_t stream) {
    const float* X  = (const float*)d_in[0];
    const float* Wq = (const float*)d_in[1];
    const float* Wk = (const float*)d_in[2];
    const float* Wv = (const float*)d_in[3];
    unsigned short* ws = (unsigned short*)d_ws;
    const size_t SZ = (size_t)16384 * 64;
    unsigned short* Qhi  = ws;
    unsigned short* Qlo  = ws + SZ;
    unsigned short* Khi  = ws + 2 * SZ;
    unsigned short* Klo  = ws + 3 * SZ;
    unsigned short* Vthi = ws + 4 * SZ;
    unsigned short* Wthi = ws + 5 * SZ;
    unsigned short* Wtlo = Wthi + 192 * 1024;

    wprep_kernel<<<48, 256, 0, stream>>>(Wq, Wk, Wv, Wthi, Wtlo);
    qkv_kernel<<<dim3(256, 2), 256, 0, stream>>>(X, Wthi, Wtlo,
                                                 Qhi, Qlo, Khi, Klo, Vthi);
    attn_kernel<<<512, 256, 0, stream>>>(Qhi, Qlo, Khi, Klo, Vthi, (float*)d_out);
}